// Round 2
// baseline (417.961 us; speedup 1.0000x reference)
//
#include <hip/hip_runtime.h>
#include <hip/hip_bf16.h>
#include <stdint.h>

#define QB 127.0f
#define EPS_G 1e-5f
#define K_DIM 4096
#define N_DIM 4096
#define BM 128
#define BN 128
#define BK 64

typedef int v4i __attribute__((ext_vector_type(4)));

#define GLOAD16(gp, lp)                                                        \
  __builtin_amdgcn_global_load_lds(                                            \
      (const __attribute__((address_space(1))) void*)(gp),                     \
      (__attribute__((address_space(3))) void*)(lp), 16, 0, 0)

// ---------------------------------------------------------------------------
// Kernel 1: weight fp32 {-1,0,1} -> int8. 4 elements/thread.
// ---------------------------------------------------------------------------
__global__ __launch_bounds__(256) void quant_w_kernel(
    const float* __restrict__ w, signed char* __restrict__ wq) {
  const int idx = blockIdx.x * 256 + threadIdx.x;
  const float4 v = ((const float4*)w)[idx];
  char4 q;
  q.x = (signed char)(int)v.x;
  q.y = (signed char)(int)v.y;
  q.z = (signed char)(int)v.z;
  q.w = (signed char)(int)v.w;
  ((char4*)wq)[idx] = q;
}

// ---------------------------------------------------------------------------
// Kernel 2: per-row absmax quant of x. One block (256 thr) per row of 4096.
// Each thread: 16 floats (4x float4), block absmax reduce, rint quantize.
// ---------------------------------------------------------------------------
__global__ __launch_bounds__(256) void quant_x_kernel(
    const float* __restrict__ x, signed char* __restrict__ xq,
    float* __restrict__ gamma_out) {
  const int row = blockIdx.x;
  const int t = threadIdx.x;
  const float4* xr = (const float4*)(x + (size_t)row * K_DIM);
  float4 v[4];
  float m = 0.f;
#pragma unroll
  for (int i = 0; i < 4; ++i) {
    v[i] = xr[t + i * 256];
    m = fmaxf(m, fmaxf(fmaxf(fabsf(v[i].x), fabsf(v[i].y)),
                       fmaxf(fabsf(v[i].z), fabsf(v[i].w))));
  }
#pragma unroll
  for (int o = 32; o > 0; o >>= 1) m = fmaxf(m, __shfl_xor(m, o));
  __shared__ float red[4];
  if ((t & 63) == 0) red[t >> 6] = m;
  __syncthreads();
  m = fmaxf(fmaxf(red[0], red[1]), fmaxf(red[2], red[3]));
  const float gamma = fmaxf(m, EPS_G);
  if (t == 0) gamma_out[row] = gamma;
  const float inv = QB / gamma;  // reference computes QB/gamma then x*that
  char4* xqr = (char4*)(xq + (size_t)row * K_DIM);
#pragma unroll
  for (int i = 0; i < 4; ++i) {
    const float a = fminf(fmaxf(rintf(v[i].x * inv), -QB), QB);
    const float b = fminf(fmaxf(rintf(v[i].y * inv), -QB), QB);
    const float c = fminf(fmaxf(rintf(v[i].z * inv), -QB), QB);
    const float d = fminf(fmaxf(rintf(v[i].w * inv), -QB), QB);
    char4 q;
    q.x = (signed char)(int)a;
    q.y = (signed char)(int)b;
    q.z = (signed char)(int)c;
    q.w = (signed char)(int)d;
    xqr[t + i * 256] = q;
  }
}

// ---------------------------------------------------------------------------
// Kernel 3: i8 GEMM, m97 structure. C[m][n] = sum_k A[m][k]*B[n][k].
// 128x128 tile, BK=64, 256 threads = 4 waves (2x2), each wave 64x64 out.
// LDS tiles are [128 rows][64 bytes] -> wave64 ds_read_b128 fragment reads
// cover all 32 banks evenly (no swizzle needed, same geometry as m97 bf16).
// global_load_lds width=16: LDS dest is wave-uniform base + lane*16; linear
// chunk c = t + 256*r maps to (row=c>>2, 16B-slot=c&3) of the tile.
// ---------------------------------------------------------------------------
__global__ __launch_bounds__(256) void gemm_i8_kernel(
    const signed char* __restrict__ A,   // [M][K] quantized activations
    const signed char* __restrict__ Bq,  // [N][K] ternary weights as i8
    const float* __restrict__ gamma,     // [M]
    const float* __restrict__ scale_p,   // [1]
    float* __restrict__ C,               // [M][N] fp32
    int M) {
  __shared__ signed char lA[BM * BK];
  __shared__ signed char lB[BN * BK];

  const int t = threadIdx.x;
  const int lane = t & 63;
  const int wave = t >> 6;
  const int wr = wave >> 1;
  const int wc = wave & 1;

  // XCD-aware bijective swizzle (nwg = 2048, divisible by 8)
  const int nwg = gridDim.x;
  const int q8 = nwg >> 3;
  const int bid = blockIdx.x;
  const int swz = (bid & 7) * q8 + (bid >> 3);
  const int nbx = N_DIM / BN;  // 32
  const int brow = (swz / nbx) * BM;
  const int bcol = (swz % nbx) * BN;

  // Staging source addresses (per thread, 2 chunks per tile)
  const int c0 = t, c1 = t + 256;
  const signed char* gA0 = A + (size_t)(brow + (c0 >> 2)) * K_DIM + (c0 & 3) * 16;
  const signed char* gA1 = A + (size_t)(brow + (c1 >> 2)) * K_DIM + (c1 & 3) * 16;
  const signed char* gB0 = Bq + (size_t)(bcol + (c0 >> 2)) * K_DIM + (c0 & 3) * 16;
  const signed char* gB1 = Bq + (size_t)(bcol + (c1 >> 2)) * K_DIM + (c1 & 3) * 16;

  // Wave-uniform LDS destinations
  signed char* lAp0 = &lA[wave * 1024];
  signed char* lAp1 = &lA[4096 + wave * 1024];
  signed char* lBp0 = &lB[wave * 1024];
  signed char* lBp1 = &lB[4096 + wave * 1024];

  v4i acc[4][4];
#pragma unroll
  for (int i = 0; i < 4; ++i)
#pragma unroll
    for (int j = 0; j < 4; ++j) acc[i][j] = (v4i){0, 0, 0, 0};

  const int ar = wr * 64 + (lane & 15);   // A fragment row within tile
  const int br = wc * 64 + (lane & 15);   // B fragment row (=out col) within tile
  const int ks = (lane >> 4) * 16;        // 16-byte K chunk per lane group

  for (int k0 = 0; k0 < K_DIM; k0 += BK) {
    GLOAD16(gA0 + k0, lAp0);
    GLOAD16(gA1 + k0, lAp1);
    GLOAD16(gB0 + k0, lBp0);
    GLOAD16(gB1 + k0, lBp1);
    __syncthreads();  // compiler emits vmcnt(0) drain before barrier

    v4i af[4], bf[4];
#pragma unroll
    for (int m = 0; m < 4; ++m)
      af[m] = *(const v4i*)&lA[(ar + m * 16) * BK + ks];
#pragma unroll
    for (int n = 0; n < 4; ++n)
      bf[n] = *(const v4i*)&lB[(br + n * 16) * BK + ks];

#pragma unroll
    for (int m = 0; m < 4; ++m)
#pragma unroll
      for (int n = 0; n < 4; ++n)
        acc[m][n] =
            __builtin_amdgcn_mfma_i32_16x16x64_i8(af[m], bf[n], acc[m][n], 0, 0, 0);
    __syncthreads();
  }

  // Epilogue: out = (acc * (gamma/QB)) * scale  (reference op order)
  const float scl = *scale_p;
  const int col0 = bcol + wc * 64 + (lane & 15);
  const int row0 = brow + wr * 64 + ((lane >> 4) << 2);
#pragma unroll
  for (int m = 0; m < 4; ++m) {
#pragma unroll
    for (int j = 0; j < 4; ++j) {
      const int row = row0 + m * 16 + j;
      const float g = gamma[row] / QB;
#pragma unroll
      for (int n = 0; n < 4; ++n) {
        const int col = col0 + n * 16;
        C[(size_t)row * N_DIM + col] = ((float)acc[m][n][j] * g) * scl;
      }
    }
  }
}

// ---------------------------------------------------------------------------
extern "C" void kernel_launch(void* const* d_in, const int* in_sizes, int n_in,
                              void* d_out, int out_size, void* d_ws, size_t ws_size,
                              hipStream_t stream) {
  const float* x = (const float*)d_in[0];      // [B*S, K] = [8192, 4096]
  const float* w = (const float*)d_in[1];      // [N, K]   = [4096, 4096]
  const float* scale = (const float*)d_in[2];  // [1]
  float* out = (float*)d_out;                  // [8192, 4096]

  const int M = in_sizes[0] / K_DIM;  // 8192

  // Workspace layout: wq [N*K] i8 | xq [M*K] i8 | gamma [M] f32  (~50.4 MB)
  signed char* wq = (signed char*)d_ws;
  signed char* xq = wq + (size_t)N_DIM * K_DIM;
  float* gamma = (float*)(xq + (size_t)M * K_DIM);

  quant_w_kernel<<<(N_DIM * K_DIM / 4) / 256, 256, 0, stream>>>(w, wq);
  quant_x_kernel<<<M, 256, 0, stream>>>(x, xq, gamma);

  const int nwg = (M / BM) * (N_DIM / BN);  // 64*32 = 2048
  gemm_i8_kernel<<<nwg, 256, 0, stream>>>(xq, wq, gamma, scale, out, M);
}

// Round 3
// 383.426 us; speedup vs baseline: 1.0901x; 1.0901x over previous
//
#include <hip/hip_runtime.h>
#include <hip/hip_bf16.h>
#include <stdint.h>

#define QB 127.0f
#define EPS_G 1e-5f
#define KD 4096
#define ND 4096
#define BM 256
#define BN 256
#define BKB 128           // K-bytes (= i8 elements) per K-tile
#define NT (KD / BKB)     // 32 K-tiles
#define NI (NT / 2)       // 16 iterations, 2 K-tiles each

typedef int v4i __attribute__((ext_vector_type(4)));

#define GLOAD16(gp, lp)                                                        \
  __builtin_amdgcn_global_load_lds(                                            \
      (const __attribute__((address_space(1))) void*)(gp),                     \
      (__attribute__((address_space(3))) void*)(lp), 16, 0, 0)

#define BAR  __builtin_amdgcn_s_barrier()
#define SB0  __builtin_amdgcn_sched_barrier(0)
#define WLG0 asm volatile("s_waitcnt lgkmcnt(0)" ::: "memory")
#define WLG8 asm volatile("s_waitcnt lgkmcnt(8)" ::: "memory")
#define WVM4 asm volatile("s_waitcnt vmcnt(4)" ::: "memory")

// ---------------------------------------------------------------------------
// Fused quant: blocks [0,M) quantize x rows (absmax int8); blocks [M,M+N)
// convert w rows {-1,0,1} fp32 -> i8. One row of 4096 per 256-thread block.
// ---------------------------------------------------------------------------
__global__ __launch_bounds__(256) void quant_fused_kernel(
    const float* __restrict__ x, const float* __restrict__ w,
    signed char* __restrict__ xq, signed char* __restrict__ wq,
    float* __restrict__ gamma_out, int M) {
  const int b = blockIdx.x;
  const int t = threadIdx.x;
  if (b < M) {
    const float4* xr = (const float4*)(x + (size_t)b * KD);
    float4 v[4];
    float m = 0.f;
#pragma unroll
    for (int i = 0; i < 4; ++i) {
      v[i] = xr[t + i * 256];
      m = fmaxf(m, fmaxf(fmaxf(fabsf(v[i].x), fabsf(v[i].y)),
                         fmaxf(fabsf(v[i].z), fabsf(v[i].w))));
    }
#pragma unroll
    for (int o = 32; o > 0; o >>= 1) m = fmaxf(m, __shfl_xor(m, o));
    __shared__ float red[4];
    if ((t & 63) == 0) red[t >> 6] = m;
    __syncthreads();
    m = fmaxf(fmaxf(red[0], red[1]), fmaxf(red[2], red[3]));
    const float gamma = fmaxf(m, EPS_G);
    if (t == 0) gamma_out[b] = gamma;
    const float inv = QB / gamma;
    char4* xqr = (char4*)(xq + (size_t)b * KD);
#pragma unroll
    for (int i = 0; i < 4; ++i) {
      char4 q;
      q.x = (signed char)(int)fminf(fmaxf(rintf(v[i].x * inv), -QB), QB);
      q.y = (signed char)(int)fminf(fmaxf(rintf(v[i].y * inv), -QB), QB);
      q.z = (signed char)(int)fminf(fmaxf(rintf(v[i].z * inv), -QB), QB);
      q.w = (signed char)(int)fminf(fmaxf(rintf(v[i].w * inv), -QB), QB);
      xqr[t + i * 256] = q;
    }
  } else {
    const int row = b - M;
    const float4* wr_ = (const float4*)(w + (size_t)row * KD);
    char4* wqr = (char4*)(wq + (size_t)row * KD);
#pragma unroll
    for (int i = 0; i < 4; ++i) {
      const float4 v = wr_[t + i * 256];
      char4 q;
      q.x = (signed char)(int)v.x;
      q.y = (signed char)(int)v.y;
      q.z = (signed char)(int)v.z;
      q.w = (signed char)(int)v.w;
      wqr[t + i * 256] = q;
    }
  }
}

// ---------------------------------------------------------------------------
// 256x256 8-phase i8 GEMM (T1+T2+T3+T4+T5). 512 thr = 8 waves (2M x 4N),
// per-wave out 128x64. BK=128 i8 (128 B rows, byte-identical to bf16 BK=64
// template). LDS 128 KiB: A[2][256][128] | B[2][256][128], XOR-swizzled
// col ^= (row&7)<<4 (conflict-free ds_read_b128), applied as pre-swizzled
// global source + swizzled read; global_load_lds dest stays linear.
// Counted vmcnt(4) at phases 4/8 only; raw barriers; never drain in-loop.
// ---------------------------------------------------------------------------
__global__ __launch_bounds__(512, 2) void gemm_i8_8ph_kernel(
    const signed char* __restrict__ A,   // [M][K] int8 activations
    const signed char* __restrict__ B,   // [N][K] int8 ternary weights
    const float* __restrict__ gamma,     // [M]
    const float* __restrict__ scale_p,   // [1]
    float* __restrict__ C) {             // [M][N] fp32
  extern __shared__ signed char lds[];
  signed char* ldsA = lds;           // 2 x 32768
  signed char* ldsB = lds + 65536;   // 2 x 32768

  const int t = threadIdx.x;
  const int lane = t & 63;
  const int wave = t >> 6;
  const int wr = wave >> 2;          // 0..1  M-half of tile
  const int wcol = wave & 3;         // 0..3  N-quarter of tile
  const int lr = lane & 15;
  const int lc = (lane >> 4) << 4;   // frag byte-col slot
  const int swzm = (lr & 7) << 4;    // read-side swizzle

  // XCD-aware bijective swizzle (512 blocks, 512 % 8 == 0)
  const int bid = blockIdx.x;
  const int swz = (bid & 7) * 64 + (bid >> 3);
  const int brow = (swz >> 4) * BM;  // 32 row-tiles
  const int bcol = (swz & 15) * BN;  // 16 col-tiles

  // Staging constants: chunk c -> (row_in_half = c>>3, slot = c&7); global
  // col pre-swizzled by the same involution the reader applies.
  const int c0 = t, c1 = t + 512;
  const int r0 = c0 >> 3, r1 = c1 >> 3;
  const int g0 = ((c0 & 7) << 4) ^ ((r0 & 7) << 4);
  const int g1 = ((c1 & 7) << 4) ^ ((r1 & 7) << 4);
  const signed char* sA0 = A + (size_t)(brow + r0) * KD + g0;
  const signed char* sA1 = A + (size_t)(brow + r1) * KD + g1;
  const signed char* sB0 = B + (size_t)(bcol + r0) * KD + g0;
  const signed char* sB1 = B + (size_t)(bcol + r1) * KD + g1;

#define STAGE_A(d, h, kt)                                                      \
  do {                                                                         \
    GLOAD16(sA0 + (size_t)(h) * 128 * KD + (kt) * BKB,                         \
            ldsA + (d) * 32768 + (h) * 16384 + c0 * 16);                       \
    GLOAD16(sA1 + (size_t)(h) * 128 * KD + (kt) * BKB,                         \
            ldsA + (d) * 32768 + (h) * 16384 + c1 * 16);                       \
  } while (0)
#define STAGE_B(d, h, kt)                                                      \
  do {                                                                         \
    GLOAD16(sB0 + (size_t)(h) * 128 * KD + (kt) * BKB,                         \
            ldsB + (d) * 32768 + (h) * 16384 + c0 * 16);                       \
    GLOAD16(sB1 + (size_t)(h) * 128 * KD + (kt) * BKB,                         \
            ldsB + (d) * 32768 + (h) * 16384 + c1 * 16);                       \
  } while (0)

#define LDA_H(d, mh)                                                           \
  _Pragma("unroll") for (int m_ = 0; m_ < 4; ++m_)                             \
  _Pragma("unroll") for (int k_ = 0; k_ < 2; ++k_)                             \
    af[m_][k_] = *(const v4i*)(ldsA + (d) * 32768 +                            \
        (wr * 128 + (mh) * 64 + m_ * 16 + lr) * 128 + ((k_ * 64 + lc) ^ swzm))
#define LDB_P(d, nh)                                                           \
  _Pragma("unroll") for (int n_ = 0; n_ < 2; ++n_)                             \
  _Pragma("unroll") for (int k_ = 0; k_ < 2; ++k_)                             \
    bf[(nh) * 2 + n_][k_] = *(const v4i*)(ldsB + (d) * 32768 +                 \
        (wcol * 64 + (nh) * 32 + n_ * 16 + lr) * 128 + ((k_ * 64 + lc) ^ swzm))

#define MFMA_Q(mh, nh)                                                         \
  do {                                                                         \
    __builtin_amdgcn_s_setprio(1);                                             \
    _Pragma("unroll") for (int m_ = 0; m_ < 4; ++m_)                           \
    _Pragma("unroll") for (int n_ = 0; n_ < 2; ++n_)                           \
    _Pragma("unroll") for (int k_ = 0; k_ < 2; ++k_)                           \
      acc[(mh) * 4 + m_][(nh) * 2 + n_] = __builtin_amdgcn_mfma_i32_16x16x64_i8( \
          af[m_][k_], bf[(nh) * 2 + n_][k_], acc[(mh) * 4 + m_][(nh) * 2 + n_], \
          0, 0, 0);                                                            \
    __builtin_amdgcn_s_setprio(0);                                             \
  } while (0)

  v4i acc[8][4];
#pragma unroll
  for (int i = 0; i < 8; ++i)
#pragma unroll
    for (int j = 0; j < 4; ++j) acc[i][j] = (v4i){0, 0, 0, 0};
  v4i af[4][2], bf[4][2];

  // Prologue: tile0 (4 halves, oldest) + tile1 B halves; wait tile0 landed.
  STAGE_B(0, 0, 0); STAGE_B(0, 1, 0); STAGE_A(0, 0, 0); STAGE_A(0, 1, 0);
  STAGE_B(1, 0, 1); STAGE_B(1, 1, 1);
  WVM4;
  BAR; SB0;

#pragma unroll 1
  for (int i = 0; i < NI; ++i) {
    const int kc1 = 2 * i + 1;            // buf1 tile (A halves staged ph1-2)
    const int kn2 = (2 * i + 2) & (NT - 1);
    const int kn3 = (2 * i + 3) & (NT - 1);

    // ---- K-tile 2i from buf0 ----
    LDA_H(0, 0); LDB_P(0, 0); STAGE_A(1, 0, kc1); WLG8;
    BAR; WLG0; SB0; MFMA_Q(0, 0); SB0; BAR; SB0;      // ph1

    LDB_P(0, 1); STAGE_A(1, 1, kc1);
    BAR; WLG0; SB0; MFMA_Q(0, 1); SB0; BAR; SB0;      // ph2

    LDA_H(0, 1); STAGE_B(0, 0, kn2);
    BAR; WLG0; SB0; MFMA_Q(1, 0); SB0; BAR; SB0;      // ph3

    STAGE_B(0, 1, kn2); WVM4;
    BAR; SB0; MFMA_Q(1, 1); SB0; BAR; SB0;            // ph4 (tile 2i+1 ready)

    // ---- K-tile 2i+1 from buf1 ----
    LDA_H(1, 0); LDB_P(1, 0); STAGE_A(0, 0, kn2); WLG8;
    BAR; WLG0; SB0; MFMA_Q(0, 0); SB0; BAR; SB0;      // ph5

    LDB_P(1, 1); STAGE_A(0, 1, kn2);
    BAR; WLG0; SB0; MFMA_Q(0, 1); SB0; BAR; SB0;      // ph6

    LDA_H(1, 1); STAGE_B(1, 0, kn3);
    BAR; WLG0; SB0; MFMA_Q(1, 0); SB0; BAR; SB0;      // ph7

    STAGE_B(1, 1, kn3); WVM4;
    BAR; SB0; MFMA_Q(1, 1); SB0; BAR; SB0;            // ph8 (tile 2i+2 ready)
  }

  // Epilogue: out = (acc * (gamma/QB)) * scale, nontemporal (no re-read).
  const float scl = *scale_p;
  const int ccol0 = bcol + wcol * 64 + lr;
  const int crow0 = brow + wr * 128 + (lane >> 4) * 4;
#pragma unroll
  for (int m_ = 0; m_ < 8; ++m_) {
#pragma unroll
    for (int j = 0; j < 4; ++j) {
      const int row = crow0 + m_ * 16 + j;
      const float g = gamma[row] / QB;
#pragma unroll
      for (int n_ = 0; n_ < 4; ++n_) {
        __builtin_nontemporal_store(((float)acc[m_][n_][j] * g) * scl,
                                    &C[(size_t)row * ND + ccol0 + n_ * 16]);
      }
    }
  }
#undef STAGE_A
#undef STAGE_B
#undef LDA_H
#undef LDB_P
#undef MFMA_Q
}

// ---------------------------------------------------------------------------
extern "C" void kernel_launch(void* const* d_in, const int* in_sizes, int n_in,
                              void* d_out, int out_size, void* d_ws, size_t ws_size,
                              hipStream_t stream) {
  const float* x = (const float*)d_in[0];      // [M, K] = [8192, 4096]
  const float* w = (const float*)d_in[1];      // [N, K] = [4096, 4096]
  const float* scale = (const float*)d_in[2];  // [1]
  float* out = (float*)d_out;                  // [M, N]

  const int M = in_sizes[0] / KD;  // 8192

  // Workspace: wq [N*K] i8 | xq [M*K] i8 | gamma [M] f32
  signed char* wq = (signed char*)d_ws;
  signed char* xq = wq + (size_t)ND * KD;
  float* gamma = (float*)(xq + (size_t)M * KD);

  quant_fused_kernel<<<M + ND, 256, 0, stream>>>(x, w, xq, wq, gamma, M);

  const int nwg = (M / BM) * (ND / BN);  // 32*16 = 512
  gemm_i8_8ph_kernel<<<nwg, 512, 131072, stream>>>(xq, wq, gamma, scale, out);
}